// Round 15
// baseline (444.547 us; speedup 1.0000x reference)
//
#include <hip/hip_runtime.h>
#include <hip/hip_bf16.h>
#include <math.h>

#define N_NODES 10000
#define N_PAD   10048       // 157 * 64
#define N_EDGES 320000
#define DIM     176
#define ATT     16
#define SH_HEADS 16
#define THH     4
#define NH      20          // SH_HEADS + TH
#define VD      11          // DIM / SH_HEADS
#define ZDIM    16
#define RDIM    16
#define QK_W    (NH*ATT)    // 320
#define QKV_W   816         // 320+320+176
#define UI_W    (2*DIM)     // 352
#define KQ      192         // padded K for qkv gemm
#define SIGINV  3.5714285714285716f   // (RDIM-1)/(CUT-RSTART)
#define RSTEP   0.28f                 // (CUT-RSTART)/(RDIM-1)

typedef unsigned short ushort_t;
typedef __attribute__((ext_vector_type(8))) short bf16x8;
typedef __attribute__((ext_vector_type(4))) float f32x4;

// ---------------- helpers ----------------

__device__ __forceinline__ ushort_t f2bf(float f) {
    __hip_bfloat16 b = __float2bfloat16(f);
    return *(ushort_t*)&b;
}

__device__ __forceinline__ float bf2f(ushort_t u) {
    return __uint_as_float(((unsigned)u) << 16);
}

__device__ __forceinline__ void sph16(float x, float y, float z, float* Y) {
    const float s3  = 1.7320508075688772f;
    const float s15 = 3.872983346207417f;
    const float c1  = 0.7905694150420949f;
    const float c2  = 0.6123724356957945f;
    float x2 = x*x, y2 = y*y, z2 = z*z;
    Y[0]  = 1.0f;
    Y[1]  = x;
    Y[2]  = y;
    Y[3]  = z;
    Y[4]  = s3 * x * y;
    Y[5]  = s3 * y * z;
    Y[6]  = 0.5f * (3.0f * z2 - 1.0f);
    Y[7]  = s3 * x * z;
    Y[8]  = 0.5f * s3 * (x2 - y2);
    Y[9]  = c1 * y * (3.0f * x2 - y2);
    Y[10] = s15 * x * y * z;
    Y[11] = c2 * y * (5.0f * z2 - 1.0f);
    Y[12] = 0.5f * z * (5.0f * z2 - 3.0f);
    Y[13] = c2 * x * (5.0f * z2 - 1.0f);
    Y[14] = 0.5f * s15 * z * (x2 - y2);
    Y[15] = c1 * x * (x2 - 3.0f * y2);
}

__device__ __forceinline__ void unpack8(const uint4 u, float* f) {
    f[0] = __uint_as_float(u.x << 16);
    f[1] = __uint_as_float(u.x & 0xffff0000u);
    f[2] = __uint_as_float(u.y << 16);
    f[3] = __uint_as_float(u.y & 0xffff0000u);
    f[4] = __uint_as_float(u.z << 16);
    f[5] = __uint_as_float(u.z & 0xffff0000u);
    f[6] = __uint_as_float(u.w << 16);
    f[7] = __uint_as_float(u.w & 0xffff0000u);
}

// ---------------- CSR build ----------------

__global__ __launch_bounds__(256) void k_deg(const int* edst, int* deg) {
    int e = blockIdx.x * 256 + threadIdx.x;
    if (e < N_EDGES) atomicAdd(&deg[edst[e]], 1);
}

__global__ __launch_bounds__(1024) void k_scan1(const int* deg, int* incl, int* bsum) {
    __shared__ int sd[1024];
    int b = blockIdx.x, tid = threadIdx.x;
    int gi = b * 1024 + tid;
    int v = (gi < N_NODES) ? deg[gi] : 0;
    sd[tid] = v;
    __syncthreads();
    for (int s = 1; s < 1024; s <<= 1) {
        int add = (tid >= s) ? sd[tid - s] : 0;
        __syncthreads();
        sd[tid] += add;
        __syncthreads();
    }
    if (gi < N_NODES) incl[gi] = sd[tid];
    if (tid == 1023) bsum[b] = sd[1023];
}

__global__ __launch_bounds__(1024) void k_scan3(const int* deg, const int* incl, const int* bsum,
                                                int* off, int* cursor) {
    __shared__ int bpre_s;
    int b = blockIdx.x, tid = threadIdx.x;
    if (tid == 0) {
        int acc = 0;
        for (int k = 0; k < b; k++) acc += bsum[k];
        bpre_s = acc;
    }
    __syncthreads();
    int gi = b * 1024 + tid;
    if (gi < N_NODES) {
        int e = bpre_s + incl[gi];
        off[gi + 1] = e;
        cursor[gi]  = e - deg[gi];
    }
    if (gi == 0) off[0] = 0;
}

// merged scatter + reorder
__global__ __launch_bounds__(256) void k_scatter_reorder(const int* esrc, const int* edst,
        const float* dist, const float* swit, const float* vec, int* cursor,
        int* src_c, int* dst_c, float* dist_c, float* sc_c, float* Yf) {
    int e = blockIdx.x * 256 + threadIdx.x;
    if (e >= N_EDGES) return;
    int t_ = edst[e];
    int p = atomicAdd(&cursor[t_], 1);
    float d = dist[e];
    float inv = 1.0f / d;
    float vx = vec[(size_t)e*3 + 0] * inv;
    float vy = vec[(size_t)e*3 + 1] * inv;
    float vz = vec[(size_t)e*3 + 2] * inv;
    src_c[p]  = esrc[e];
    dst_c[p]  = t_;
    dist_c[p] = d;
    sc_c[p]   = swit[e] * 0.25f;           // switch / sqrt(ATT)
    float Y[16];
    sph16(vx, vy, vz, Y);
    #pragma unroll
    for (int m = 0; m < 16; m += 4)
        *(float4*)&Yf[(size_t)p * 16 + m] = make_float4(Y[m], Y[m+1], Y[m+2], Y[m+3]);
}

// ---------------- combined weight prep ----------------

__device__ __forceinline__ void prep_qkv_body(int bid, int tid, const float* wq,
        const float* wk, const float* wv, ushort_t* Wtq) {
    int id = bid * 256 + tid;
    if (id >= 192 * 832) return;
    int k = id / 832, n = id - (id / 832) * 832;
    float v = 0.0f;
    if (k < DIM && n < QKV_W)
        v = (n < 320) ? wq[k * 320 + n] : (n < 640) ? wk[k * 320 + (n - 320)]
                                                    : wv[k * DIM + (n - 640)];
    Wtq[(size_t)n * KQ + k] = f2bf(v);
}

__device__ __forceinline__ void prep_upd_body(int bid, int tid, const float* uw, ushort_t* Wtu) {
    int id = bid * 256 + tid;
    if (id >= 352 * 192) return;
    int k = id / 192, n = id - (id / 192) * 192;
    float v = (n < DIM) ? uw[k * DIM + n] : 0.0f;
    Wtu[(size_t)n * UI_W + k] = f2bf(v);
}

__device__ __forceinline__ void prep_mlp_body(int bid, int tid, const float* pw1,
        const float* pw2, ushort_t* w1T, ushort_t* w2T, int K1) {
    int id = bid * 256 + tid;
    if (id < 1024) {
        int n = id >> 5, k = id & 31;
        w1T[n * 32 + k] = (k < K1) ? f2bf(pw1[k * 32 + n]) : 0;
    } else if (id < 1536) {
        int id2 = id - 1024;
        int n = id2 >> 5, k = id2 & 31;
        w2T[n * 32 + k] = f2bf(pw2[k * 16 + n]);
    }
}

__global__ __launch_bounds__(256) void k_prep_all(
        const float* wq0, const float* wk0, const float* wv0, ushort_t* Wtq0,
        const float* wq1, const float* wk1, const float* wv1, ushort_t* Wtq1,
        const float* uw0, ushort_t* Wtu0, const float* uw1, ushort_t* Wtu1,
        const float* pw1_0, const float* pw2_0, ushort_t* w1T0, ushort_t* w2T0,
        const float* pw1_1, const float* pw2_1, ushort_t* w1T1, ushort_t* w2T1) {
    int bid = blockIdx.x, tid = threadIdx.x;
    if (bid < 624)        prep_qkv_body(bid,        tid, wq0, wk0, wv0, Wtq0);
    else if (bid < 1248)  prep_qkv_body(bid - 624,  tid, wq1, wk1, wv1, Wtq1);
    else if (bid < 1512)  prep_upd_body(bid - 1248, tid, uw0, Wtu0);
    else if (bid < 1776)  prep_upd_body(bid - 1512, tid, uw1, Wtu1);
    else if (bid < 1782)  prep_mlp_body(bid - 1776, tid, pw1_0, pw2_0, w1T0, w2T0, 16);
    else if (bid < 1788)  prep_mlp_body(bid - 1782, tid, pw1_1, pw2_1, w1T1, w2T1, 32);
}

// ---------------- MFMA GEMM (qkv only: split bf16 qh/kh/vh) ----------------

template<int KCHUNKS>
__global__ __launch_bounds__(256) void k_gemm(const ushort_t* __restrict__ A, int sA,
                                              const ushort_t* __restrict__ Bt, int sB,
                                              int M, int N,
                                              ushort_t* __restrict__ qh,
                                              ushort_t* __restrict__ kh,
                                              ushort_t* __restrict__ vh) {
    __shared__ ushort_t As[64 * 40];
    __shared__ ushort_t Bs[64 * 40];
    int tid  = threadIdx.x;
    int m0   = blockIdx.y * 64, n0 = blockIdx.x * 64;
    int w    = tid >> 6, lane = tid & 63, quad = lane >> 4, c16 = lane & 15;
    int arow = tid >> 2, aseg = tid & 3;
    f32x4 acc[4] = {};
    for (int kc = 0; kc < KCHUNKS; kc++) {
        int k0 = kc * 32;
        *(uint4*)&As[arow * 40 + aseg * 8] =
            *(const uint4*)&A[(size_t)(m0 + arow) * sA + k0 + aseg * 8];
        *(uint4*)&Bs[arow * 40 + aseg * 8] =
            *(const uint4*)&Bt[(size_t)(n0 + arow) * sB + k0 + aseg * 8];
        __syncthreads();
        bf16x8 a = *(const bf16x8*)&As[(w * 16 + c16) * 40 + quad * 8];
        #pragma unroll
        for (int t = 0; t < 4; t++) {
            bf16x8 b = *(const bf16x8*)&Bs[(t * 16 + c16) * 40 + quad * 8];
            acc[t] = __builtin_amdgcn_mfma_f32_16x16x32_bf16(a, b, acc[t], 0, 0, 0);
        }
        __syncthreads();
    }
    #pragma unroll
    for (int t = 0; t < 4; t++) {
        #pragma unroll
        for (int r = 0; r < 4; r++) {
            int row = m0 + w * 16 + quad * 4 + r;
            int col = n0 + t * 16 + c16;
            if (row < M && col < N) {
                ushort_t bv = f2bf(acc[t][r]);
                if (col < 320)      qh[(size_t)row * QK_W + col] = bv;
                else if (col < 640) kh[(size_t)row * QK_W + (col - 320)] = bv;
                else                vh[(size_t)row * DIM  + (col - 640)] = bv;
            }
        }
    }
}

// ---------------- fused update GEMM + LN: xo = LN(xi + cxm@Wtu + ub) ------------
// one block per 64 rows; 3 n-tiles cover all 176 output cols; LN in-block.

__global__ __launch_bounds__(256) void k_updln(const ushort_t* __restrict__ cxmIn,
        const ushort_t* __restrict__ Wtu, const float* __restrict__ xi,
        const float* __restrict__ ub,
        float* xo, ushort_t* xib, ushort_t* cxm) {
    __shared__ char smem[64 * 180 * 4];      // GEMM tiles, then yt[64][180]
    __shared__ float red[256];
    __shared__ float mus[64], rstds[64];
    ushort_t* As = (ushort_t*)smem;                       // 64*40 ushorts
    ushort_t* Bs = (ushort_t*)(smem + 64 * 40 * 2);       // 3 * 64*40 ushorts
    float*    yt = (float*)smem;                          // aliased after GEMM

    int tid = threadIdx.x;
    int m0  = blockIdx.x * 64;
    int w = tid >> 6, lane = tid & 63, quad = lane >> 4, c16 = lane & 15;
    int arow = tid >> 2, aseg = tid & 3;
    f32x4 acc[3][4] = {};
    for (int kc = 0; kc < 11; kc++) {
        int k0 = kc * 32;
        *(uint4*)&As[arow * 40 + aseg * 8] =
            *(const uint4*)&cxmIn[(size_t)(m0 + arow) * UI_W + k0 + aseg * 8];
        #pragma unroll
        for (int t3 = 0; t3 < 3; t3++)
            *(uint4*)&Bs[(t3 * 64 + arow) * 40 + aseg * 8] =
                *(const uint4*)&Wtu[(size_t)(t3 * 64 + arow) * UI_W + k0 + aseg * 8];
        __syncthreads();
        bf16x8 a = *(const bf16x8*)&As[(w * 16 + c16) * 40 + quad * 8];
        #pragma unroll
        for (int t3 = 0; t3 < 3; t3++) {
            #pragma unroll
            for (int t = 0; t < 4; t++) {
                bf16x8 b = *(const bf16x8*)&Bs[(t3 * 64 + t * 16 + c16) * 40 + quad * 8];
                acc[t3][t] = __builtin_amdgcn_mfma_f32_16x16x32_bf16(a, b, acc[t3][t], 0, 0, 0);
            }
        }
        __syncthreads();
    }
    // GEMM results -> yt (cols < 176 only)
    #pragma unroll
    for (int t3 = 0; t3 < 3; t3++) {
        #pragma unroll
        for (int t = 0; t < 4; t++) {
            int col = t3 * 64 + t * 16 + c16;
            if (col < DIM) {
                #pragma unroll
                for (int r = 0; r < 4; r++) {
                    int row = w * 16 + quad * 4 + r;
                    yt[row * 180 + col] = acc[t3][t][r];
                }
            }
        }
    }
    __syncthreads();
    // add residual + bias
    for (int idx = tid; idx < 64 * DIM; idx += 256) {
        int r = idx / DIM, c = idx - r * DIM;
        int grow = m0 + r;
        float base = (grow < N_NODES) ? xi[(size_t)grow * DIM + c] : 0.0f;
        yt[r * 180 + c] += base + ub[c];
    }
    __syncthreads();
    // LN: 4 threads per row
    { int r = tid >> 2, j = tid & 3;
      float s = 0.0f;
      for (int c = j; c < DIM; c += 4) s += yt[r * 180 + c];
      red[tid] = s; }
    __syncthreads();
    if (tid < 64) {
        float s = red[tid*4] + red[tid*4+1] + red[tid*4+2] + red[tid*4+3];
        mus[tid] = s / (float)DIM;
    }
    __syncthreads();
    { int r = tid >> 2, j = tid & 3;
      float mu = mus[r], s = 0.0f;
      for (int c = j; c < DIM; c += 4) { float d = yt[r * 180 + c] - mu; s += d * d; }
      red[tid] = s; }
    __syncthreads();
    if (tid < 64) {
        float s = red[tid*4] + red[tid*4+1] + red[tid*4+2] + red[tid*4+3];
        rstds[tid] = rsqrtf(s / (float)DIM + 1e-6f);
    }
    __syncthreads();
    for (int idx = tid; idx < 64 * DIM; idx += 256) {
        int r = idx / DIM, c = idx - r * DIM;
        int grow = m0 + r;
        if (grow < N_NODES) {
            float val = (yt[r * 180 + c] - mus[r]) * rstds[r];
            xo[(size_t)grow * DIM + c] = val;
            ushort_t bv = f2bf(val);
            xib[(size_t)grow * KQ + c]   = bv;
            cxm[(size_t)grow * UI_W + c] = bv;
        }
    }
}

// ---------------- node embedding ----------------

__global__ __launch_bounds__(256) void k_node_init(const int* species, const float* z_table,
                                                   const float* wsp, float* xi,
                                                   ushort_t* xib, ushort_t* cxm) {
    __shared__ float zs[16 * ZDIM];
    __shared__ float yt[16 * DIM];
    __shared__ float red[256];
    __shared__ float mus[16], rstds[16];
    int base = blockIdx.x * 16;
    int tid  = threadIdx.x;
    { int n = tid >> 4, kk = tid & 15;
      zs[tid] = z_table[species[base + n] * ZDIM + kk]; }
    __syncthreads();
    int c = tid;
    if (c < DIM) {
        float acc[16];
        #pragma unroll
        for (int n = 0; n < 16; n++) acc[n] = 0.0f;
        for (int kk = 0; kk < ZDIM; kk++) {
            float w = wsp[kk * DIM + c];
            #pragma unroll
            for (int n = 0; n < 16; n++) acc[n] += zs[n * ZDIM + kk] * w;
        }
        #pragma unroll
        for (int n = 0; n < 16; n++) yt[n * DIM + c] = acc[n];
    }
    __syncthreads();
    { int n2 = tid >> 4, j = tid & 15;
      float s = 0.0f;
      for (int c2 = j; c2 < DIM; c2 += 16) s += yt[n2 * DIM + c2];
      red[tid] = s; }
    __syncthreads();
    if (tid < 16) { float s = 0; for (int j = 0; j < 16; j++) s += red[tid * 16 + j]; mus[tid] = s / (float)DIM; }
    __syncthreads();
    { int n2 = tid >> 4, j = tid & 15;
      float mu = mus[n2], s = 0.0f;
      for (int c2 = j; c2 < DIM; c2 += 16) { float d = yt[n2 * DIM + c2] - mu; s += d * d; }
      red[tid] = s; }
    __syncthreads();
    if (tid < 16) { float s = 0; for (int j = 0; j < 16; j++) s += red[tid * 16 + j]; rstds[tid] = rsqrtf(s / (float)DIM + 1e-6f); }
    __syncthreads();
    if (c < DIM) {
        #pragma unroll
        for (int n = 0; n < 16; n++) {
            float val = (yt[n * DIM + c] - mus[n]) * rstds[n];
            xi[(size_t)(base + n) * DIM + c] = val;
            ushort_t bv = f2bf(val);
            xib[(size_t)(base + n) * KQ + c]   = bv;
            cxm[(size_t)(base + n) * UI_W + c] = bv;
        }
    } else if (c < KQ) {
        #pragma unroll
        for (int n = 0; n < 16; n++) xib[(size_t)(base + n) * KQ + c] = 0;
    }
}

// ---------------- fused edge kernel (R12 configuration) ----------------

template<bool L0>
__global__ __launch_bounds__(256) void k_edge(const float* dist_c, const float* sc_c,
        const int* src_c, const int* dst_c, const float* Yf, const ushort_t* Vih,
        const ushort_t* qh, const ushort_t* kh,
        const ushort_t* w1T, const float* pb1, const ushort_t* w2T, const float* pb2,
        ushort_t* aijh) {
    __shared__ ushort_t urS[64 * 40];
    __shared__ ushort_t Ht[4][16 * 40];
    __shared__ float    wdS[64 * 17];
    __shared__ ushort_t aS[NH][64];
    int tid  = threadIdx.x;
    int w    = tid >> 6, lane = tid & 63, quad = lane >> 4, c16 = lane & 15;
    int eb   = blockIdx.x * 64;

    if (!L0) {
        if (tid < 64) {
            int i = eb + tid;
            float d = dist_c[i];
            ushort_t u[32];
            #pragma unroll
            for (int r = 0; r < 16; r++) {
                float cc = 0.8f + (float)r * RSTEP;
                float uu = (d - cc) * SIGINV;
                u[r] = f2bf(__expf(-uu * uu));
            }
            float Y[16];
            #pragma unroll
            for (int m = 0; m < 16; m += 4) {
                float4 y = *(const float4*)&Yf[(size_t)i * 16 + m];
                Y[m] = y.x; Y[m+1] = y.y; Y[m+2] = y.z; Y[m+3] = y.w;
            }
            int s = src_c[i], t_ = dst_c[i];
            const uint4* vd4 = (const uint4*)(Vih + (size_t)t_ * 64);
            const uint4* vs4 = (const uint4*)(Vih + (size_t)s  * 64);
            #pragma unroll
            for (int th = 0; th < THH; th++) {
                float fd[16], fs[16];
                unpack8(vd4[2*th],   fd);     unpack8(vd4[2*th+1], fd+8);
                unpack8(vs4[2*th],   fs);     unpack8(vs4[2*th+1], fs+8);
                float us0 = (fd[0] + fs[0]) * Y[0];
                float us1 = 0.0f, us2 = 0.0f, us3 = 0.0f;
                #pragma unroll
                for (int m = 1; m < 4; m++)  us1 += (fd[m] - fs[m]) * Y[m];
                #pragma unroll
                for (int m = 4; m < 9; m++)  us2 += (fd[m] + fs[m]) * Y[m];
                #pragma unroll
                for (int m = 9; m < 16; m++) us3 += (fd[m] - fs[m]) * Y[m];
                u[16 + 0 * 4 + th] = f2bf(us0);
                u[16 + 1 * 4 + th] = f2bf(us1);
                u[16 + 2 * 4 + th] = f2bf(us2);
                u[16 + 3 * 4 + th] = f2bf(us3);
            }
            #pragma unroll
            for (int p = 0; p < 4; p++)
                *(uint4*)&urS[tid * 40 + p * 8] = *(uint4*)&u[p * 8];
        }
        __syncthreads();
    }

    {
        int e0 = eb + w * 16;
        bf16x8 a1;
        if (L0) {
            float d = dist_c[e0 + c16];
            #pragma unroll
            for (int j = 0; j < 8; j++) {
                int r = quad * 8 + j;
                float v = 0.0f;
                if (r < 16) { float cc = 0.8f + (float)r * RSTEP; float uu = (d - cc) * SIGINV; v = __expf(-uu * uu); }
                a1[j] = (short)f2bf(v);
            }
        } else {
            a1 = *(const bf16x8*)&urS[(w * 16 + c16) * 40 + quad * 8];
        }
        bf16x8 b0 = *(const bf16x8*)&w1T[c16 * 32 + quad * 8];
        bf16x8 b1 = *(const bf16x8*)&w1T[(16 + c16) * 32 + quad * 8];
        f32x4 acc0 = {}, acc1 = {};
        acc0 = __builtin_amdgcn_mfma_f32_16x16x32_bf16(a1, b0, acc0, 0, 0, 0);
        acc1 = __builtin_amdgcn_mfma_f32_16x16x32_bf16(a1, b1, acc1, 0, 0, 0);
        float bb0 = pb1[c16], bb1 = pb1[c16 + 16];
        #pragma unroll
        for (int r = 0; r < 4; r++) {
            int er = quad * 4 + r;
            float h0 = acc0[r] + bb0; h0 = h0 / (1.0f + __expf(-h0));
            float h1 = acc1[r] + bb1; h1 = h1 / (1.0f + __expf(-h1));
            Ht[w][er * 40 + c16]      = f2bf(h0);
            Ht[w][er * 40 + 16 + c16] = f2bf(h1);
        }
        __syncthreads();
        bf16x8 a2 = *(const bf16x8*)&Ht[w][c16 * 40 + quad * 8];
        bf16x8 b2 = *(const bf16x8*)&w2T[c16 * 32 + quad * 8];
        f32x4 acc2 = {};
        acc2 = __builtin_amdgcn_mfma_f32_16x16x32_bf16(a2, b2, acc2, 0, 0, 0);
        float bb2 = pb2[c16];
        #pragma unroll
        for (int r = 0; r < 4; r++) {
            int er = quad * 4 + r;
            wdS[(w * 16 + er) * 17 + c16] = (acc2[r] + bb2) * sc_c[e0 + er];
        }
    }
    __syncthreads();

    {
        int le = tid >> 2, part = tid & 3;
        int i  = eb + le;
        int s = src_c[i], t_ = dst_c[i];
        float wd[16];
        #pragma unroll
        for (int p = 0; p < 16; p++) wd[p] = wdS[le * 17 + p];
        const uint4* q4 = (const uint4*)(qh + (size_t)t_ * QK_W);
        const uint4* k4 = (const uint4*)(kh + (size_t)s  * QK_W);
        #pragma unroll
        for (int j = 0; j < 5; j++) {
            int h = part * 5 + j;
            float qa[8], qb[8], ka[8], kb[8];
            unpack8(q4[2*h],   qa); unpack8(q4[2*h+1], qb);
            unpack8(k4[2*h],   ka); unpack8(k4[2*h+1], kb);
            float acc = 0.0f;
            #pragma unroll
            for (int dd = 0; dd < 8; dd++) acc += qa[dd] * ka[dd] * wd[dd];
            #pragma unroll
            for (int dd = 0; dd < 8; dd++) acc += qb[dd] * kb[dd] * wd[8 + dd];
            aS[h][le] = f2bf(acc);
        }
    }
    __syncthreads();
    {
        const uint* aSw = (const uint*)aS;
        for (int idx = tid; idx < NH * 32; idx += 256) {
            int h = idx >> 5, w2 = idx & 31;
            *(uint*)(aijh + (size_t)h * N_EDGES + eb + w2 * 2) = aSw[h * 32 + w2];
        }
    }
}

// ---------------- aggregation: one wave per node for BOTH mi and Vi ----------

__device__ __forceinline__ void mi_step(int i, int c0, bool f1, bool f2,
        const int* src_c, const ushort_t* aA, const ushort_t* aB, const ushort_t* vh,
        float& acc0, float& acc1, float& acc2, float& acc3) {
    int s0 = src_c[i];
    uint2 v0 = *(const uint2*)(vh + (size_t)s0 * DIM + c0);
    float a00 = bf2f(aA[i]), a0B = bf2f(aB[i]);
    float g01 = f1 ? a0B : a00, g02 = f2 ? a0B : a00;
    acc0 += a00 * __uint_as_float(v0.x << 16);
    acc1 += g01 * __uint_as_float(v0.x & 0xffff0000u);
    acc2 += g02 * __uint_as_float(v0.y << 16);
    acc3 += a0B * __uint_as_float(v0.y & 0xffff0000u);
}

__device__ __forceinline__ void mi_wave(int n, int lane, const int* off, const int* src_c,
        const ushort_t* aijh, const ushort_t* vh, ushort_t* cxm) {
    if (lane >= 44) return;
    int c0 = lane * 4;
    int hA = c0 / VD;
    int hB = (c0 + 3) / VD;
    bool f1 = ((c0 + 1) / VD) != hA;
    bool f2 = ((c0 + 2) / VD) != hA;
    const ushort_t* aA = aijh + (size_t)hA * N_EDGES;
    const ushort_t* aB = aijh + (size_t)hB * N_EDGES;
    int start = off[n], end = off[n + 1];
    float acc0 = 0, acc1 = 0, acc2 = 0, acc3 = 0;
    int i = start;
    for (; i + 4 <= end; i += 4) {
        int s0 = src_c[i], s1 = src_c[i+1], s2 = src_c[i+2], s3 = src_c[i+3];
        uint2 v0 = *(const uint2*)(vh + (size_t)s0 * DIM + c0);
        uint2 v1 = *(const uint2*)(vh + (size_t)s1 * DIM + c0);
        uint2 v2 = *(const uint2*)(vh + (size_t)s2 * DIM + c0);
        uint2 v3 = *(const uint2*)(vh + (size_t)s3 * DIM + c0);
        float aA0 = bf2f(aA[i]),   aB0 = bf2f(aB[i]);
        float aA1 = bf2f(aA[i+1]), aB1 = bf2f(aB[i+1]);
        float aA2 = bf2f(aA[i+2]), aB2 = bf2f(aB[i+2]);
        float aA3 = bf2f(aA[i+3]), aB3 = bf2f(aB[i+3]);
        float g01 = f1 ? aB0 : aA0, g02 = f2 ? aB0 : aA0;
        float g11 = f1 ? aB1 : aA1, g12 = f2 ? aB1 : aA1;
        float g21 = f1 ? aB2 : aA2, g22 = f2 ? aB2 : aA2;
        float g31 = f1 ? aB3 : aA3, g32 = f2 ? aB3 : aA3;
        acc0 += aA0 * __uint_as_float(v0.x << 16);
        acc1 += g01 * __uint_as_float(v0.x & 0xffff0000u);
        acc2 += g02 * __uint_as_float(v0.y << 16);
        acc3 += aB0 * __uint_as_float(v0.y & 0xffff0000u);
        acc0 += aA1 * __uint_as_float(v1.x << 16);
        acc1 += g11 * __uint_as_float(v1.x & 0xffff0000u);
        acc2 += g12 * __uint_as_float(v1.y << 16);
        acc3 += aB1 * __uint_as_float(v1.y & 0xffff0000u);
        acc0 += aA2 * __uint_as_float(v2.x << 16);
        acc1 += g21 * __uint_as_float(v2.x & 0xffff0000u);
        acc2 += g22 * __uint_as_float(v2.y << 16);
        acc3 += aB2 * __uint_as_float(v2.y & 0xffff0000u);
        acc0 += aA3 * __uint_as_float(v3.x << 16);
        acc1 += g31 * __uint_as_float(v3.x & 0xffff0000u);
        acc2 += g32 * __uint_as_float(v3.y << 16);
        acc3 += aB3 * __uint_as_float(v3.y & 0xffff0000u);
    }
    for (; i < end; i++)
        mi_step(i, c0, f1, f2, src_c, aA, aB, vh, acc0, acc1, acc2, acc3);
    ushort_t o[4] = {f2bf(acc0), f2bf(acc1), f2bf(acc2), f2bf(acc3)};
    *(uint2*)(cxm + (size_t)n * UI_W + DIM + c0) = *(uint2*)o;
}

__device__ __forceinline__ void vi_wave(int n, int lane, const int* off,
        const float* Yf, const ushort_t* aijh, ushort_t* Vih) {
    int th = lane >> 4, sm = lane & 15;
    const ushort_t* ah = aijh + (size_t)(SH_HEADS + th) * N_EDGES;
    int start = off[n], end = off[n + 1];
    float acc = 0.0f;
    int i = start;
    for (; i + 4 <= end; i += 4) {
        float a0 = bf2f(ah[i]),   y0 = Yf[(size_t)i * 16 + sm];
        float a1 = bf2f(ah[i+1]), y1 = Yf[(size_t)(i+1) * 16 + sm];
        float a2 = bf2f(ah[i+2]), y2 = Yf[(size_t)(i+2) * 16 + sm];
        float a3 = bf2f(ah[i+3]), y3 = Yf[(size_t)(i+3) * 16 + sm];
        acc += a0 * y0 + a1 * y1 + a2 * y2 + a3 * y3;
    }
    for (; i < end; i++)
        acc += bf2f(ah[i]) * Yf[(size_t)i * 16 + sm];
    Vih[(size_t)n * 64 + lane] = f2bf(acc);
}

__global__ __launch_bounds__(256) void k_agg0(const int* off, const int* src_c,
        const float* Yf, const ushort_t* aijh, const ushort_t* vh,
        ushort_t* cxm, ushort_t* Vih) {
    int wid  = blockIdx.x * 4 + (threadIdx.x >> 6);
    int lane = threadIdx.x & 63;
    if (wid < N_NODES)
        mi_wave(wid, lane, off, src_c, aijh, vh, cxm);
    else
        vi_wave(wid - N_NODES, lane, off, Yf, aijh, Vih);
}

__global__ __launch_bounds__(256) void k_agg1(const int* off, const int* src_c,
        const ushort_t* aijh, const ushort_t* vh, ushort_t* cxm) {
    int wid  = blockIdx.x * 4 + (threadIdx.x >> 6);
    int lane = threadIdx.x & 63;
    mi_wave(wid, lane, off, src_c, aijh, vh, cxm);
}

// ---------------- launch ----------------

extern "C" void kernel_launch(void* const* d_in, const int* in_sizes, int n_in,
                              void* d_out, int out_size, void* d_ws, size_t ws_size,
                              hipStream_t stream) {
    const int*   species = (const int*)  d_in[0];
    const float* dist    = (const float*)d_in[1];
    const float* swit    = (const float*)d_in[2];
    const int*   esrc    = (const int*)  d_in[3];
    const int*   edst    = (const int*)  d_in[4];
    const float* vec     = (const float*)d_in[5];
    const float* z_table = (const float*)d_in[6];
    const float* wsp     = (const float*)d_in[7];
    const float* pw1_0 = (const float*)d_in[8],  *pb1_0 = (const float*)d_in[9];
    const float* pw2_0 = (const float*)d_in[10], *pb2_0 = (const float*)d_in[11];
    const float* wq0 = (const float*)d_in[12], *wk0 = (const float*)d_in[13];
    const float* wv0 = (const float*)d_in[14], *uw0 = (const float*)d_in[15];
    const float* ub0 = (const float*)d_in[16];
    const float* pw1_1 = (const float*)d_in[17], *pb1_1 = (const float*)d_in[18];
    const float* pw2_1 = (const float*)d_in[19], *pb2_1 = (const float*)d_in[20];
    const float* wq1 = (const float*)d_in[21], *wk1 = (const float*)d_in[22];
    const float* wv1 = (const float*)d_in[23], *uw1 = (const float*)d_in[24];
    const float* ub1 = (const float*)d_in[25];
    float* out = (float*)d_out;

    char* p = (char*)d_ws;
    auto alloc = [&](size_t bytes) -> char* {
        char* r = p;
        p += (bytes + 255) & ~(size_t)255;
        return r;
    };
    int* deg    = (int*)alloc((size_t)N_NODES * 4);
    int* incl   = (int*)alloc((size_t)N_NODES * 4);
    int* bsum   = (int*)alloc(64);
    int* off    = (int*)alloc((size_t)(N_NODES + 1) * 4);
    int* cursor = (int*)alloc((size_t)N_NODES * 4);
    int*   src_c  = (int*)  alloc((size_t)N_EDGES * 4);
    int*   dst_c  = (int*)  alloc((size_t)N_EDGES * 4);
    float* dist_c = (float*)alloc((size_t)N_EDGES * 4);
    float* sc_c   = (float*)alloc((size_t)N_EDGES * 4);
    float* Yf     = (float*)alloc((size_t)N_EDGES * 16 * 4);
    float* xiA  = (float*)alloc((size_t)N_NODES * DIM * 4);
    float* xiB  = (float*)alloc((size_t)N_NODES * DIM * 4);
    ushort_t* xib  = (ushort_t*)alloc((size_t)N_PAD * KQ * 2);
    ushort_t* cxm  = (ushort_t*)alloc((size_t)N_PAD * UI_W * 2);
    ushort_t* qh   = (ushort_t*)alloc((size_t)N_NODES * QK_W * 2);
    ushort_t* kh   = (ushort_t*)alloc((size_t)N_NODES * QK_W * 2);
    ushort_t* vh   = (ushort_t*)alloc((size_t)N_NODES * DIM * 2);
    ushort_t* Wtq0 = (ushort_t*)alloc((size_t)832 * KQ * 2);
    ushort_t* Wtq1 = (ushort_t*)alloc((size_t)832 * KQ * 2);
    ushort_t* Wtu0 = (ushort_t*)alloc((size_t)192 * UI_W * 2);
    ushort_t* Wtu1 = (ushort_t*)alloc((size_t)192 * UI_W * 2);
    ushort_t* w1T0 = (ushort_t*)alloc((size_t)32 * 32 * 2);
    ushort_t* w2T0 = (ushort_t*)alloc((size_t)16 * 32 * 2);
    ushort_t* w1T1 = (ushort_t*)alloc((size_t)32 * 32 * 2);
    ushort_t* w2T1 = (ushort_t*)alloc((size_t)16 * 32 * 2);
    ushort_t* Vih  = (ushort_t*)alloc((size_t)N_NODES * 64 * 2);
    ushort_t* aijh = (ushort_t*)alloc((size_t)N_EDGES * NH * 2);

    const int NB_E  = (N_EDGES + 255) / 256;   // 1250
    const int NB_F  = N_EDGES / 64;            // 5000 (fused edge kernel)
    const int NB_T  = N_NODES / 16;            // 625
    const int NB_U  = N_PAD / 64;              // 157 (fused upd+LN)
    const dim3 GRID_QKV(13, 157);

    hipMemsetAsync(deg, 0, (size_t)N_NODES * 4, stream);
    k_deg<<<NB_E, 256, 0, stream>>>(edst, deg);
    k_scan1<<<10, 1024, 0, stream>>>(deg, incl, bsum);
    k_scan3<<<10, 1024, 0, stream>>>(deg, incl, bsum, off, cursor);
    k_scatter_reorder<<<NB_E, 256, 0, stream>>>(esrc, edst, dist, swit, vec, cursor,
                                                src_c, dst_c, dist_c, sc_c, Yf);

    k_prep_all<<<1788, 256, 0, stream>>>(wq0, wk0, wv0, Wtq0, wq1, wk1, wv1, Wtq1,
                                         uw0, Wtu0, uw1, Wtu1,
                                         pw1_0, pw2_0, w1T0, w2T0,
                                         pw1_1, pw2_1, w1T1, w2T1);

    k_node_init<<<NB_T, 256, 0, stream>>>(species, z_table, wsp, xiA, xib, cxm);

    // layer 0
    k_gemm<6><<<GRID_QKV, 256, 0, stream>>>(xib, KQ, Wtq0, KQ, N_NODES, QKV_W, qh, kh, vh);
    k_edge<true><<<NB_F, 256, 0, stream>>>(dist_c, sc_c, src_c, dst_c, Yf, Vih,
                                           qh, kh, w1T0, pb1_0, w2T0, pb2_0, aijh);
    k_agg0<<<5000, 256, 0, stream>>>(off, src_c, Yf, aijh, vh, cxm, Vih);
    k_updln<<<NB_U, 256, 0, stream>>>(cxm, Wtu0, xiA, ub0, xiB, xib, cxm);

    // layer 1
    k_gemm<6><<<GRID_QKV, 256, 0, stream>>>(xib, KQ, Wtq1, KQ, N_NODES, QKV_W, qh, kh, vh);
    k_edge<false><<<NB_F, 256, 0, stream>>>(dist_c, sc_c, src_c, dst_c, Yf, Vih,
                                            qh, kh, w1T1, pb1_1, w2T1, pb2_1, aijh);
    k_agg1<<<2500, 256, 0, stream>>>(off, src_c, aijh, vh, cxm);
    k_updln<<<NB_U, 256, 0, stream>>>(cxm, Wtu1, xiB, ub1, out, xib, cxm);
}

// Round 16
// 409.753 us; speedup vs baseline: 1.0849x; 1.0849x over previous
//
#include <hip/hip_runtime.h>
#include <hip/hip_bf16.h>
#include <math.h>

#define N_NODES 10000
#define N_PAD   10048       // 157 * 64
#define N_EDGES 320000
#define DIM     176
#define ATT     16
#define SH_HEADS 16
#define THH     4
#define NH      20          // SH_HEADS + TH
#define VD      11          // DIM / SH_HEADS
#define ZDIM    16
#define RDIM    16
#define QK_W    (NH*ATT)    // 320
#define QKV_W   816         // 320+320+176
#define UI_W    (2*DIM)     // 352
#define KQ      192         // padded K for qkv gemm
#define SIGINV  3.5714285714285716f   // (RDIM-1)/(CUT-RSTART)
#define RSTEP   0.28f                 // (CUT-RSTART)/(RDIM-1)

typedef unsigned short ushort_t;
typedef __attribute__((ext_vector_type(8))) short bf16x8;
typedef __attribute__((ext_vector_type(4))) float f32x4;

// ---------------- helpers ----------------

__device__ __forceinline__ ushort_t f2bf(float f) {
    __hip_bfloat16 b = __float2bfloat16(f);
    return *(ushort_t*)&b;
}

__device__ __forceinline__ float bf2f(ushort_t u) {
    return __uint_as_float(((unsigned)u) << 16);
}

__device__ __forceinline__ void sph16(float x, float y, float z, float* Y) {
    const float s3  = 1.7320508075688772f;
    const float s15 = 3.872983346207417f;
    const float c1  = 0.7905694150420949f;
    const float c2  = 0.6123724356957945f;
    float x2 = x*x, y2 = y*y, z2 = z*z;
    Y[0]  = 1.0f;
    Y[1]  = x;
    Y[2]  = y;
    Y[3]  = z;
    Y[4]  = s3 * x * y;
    Y[5]  = s3 * y * z;
    Y[6]  = 0.5f * (3.0f * z2 - 1.0f);
    Y[7]  = s3 * x * z;
    Y[8]  = 0.5f * s3 * (x2 - y2);
    Y[9]  = c1 * y * (3.0f * x2 - y2);
    Y[10] = s15 * x * y * z;
    Y[11] = c2 * y * (5.0f * z2 - 1.0f);
    Y[12] = 0.5f * z * (5.0f * z2 - 3.0f);
    Y[13] = c2 * x * (5.0f * z2 - 1.0f);
    Y[14] = 0.5f * s15 * z * (x2 - y2);
    Y[15] = c1 * x * (x2 - 3.0f * y2);
}

__device__ __forceinline__ void unpack8(const uint4 u, float* f) {
    f[0] = __uint_as_float(u.x << 16);
    f[1] = __uint_as_float(u.x & 0xffff0000u);
    f[2] = __uint_as_float(u.y << 16);
    f[3] = __uint_as_float(u.y & 0xffff0000u);
    f[4] = __uint_as_float(u.z << 16);
    f[5] = __uint_as_float(u.z & 0xffff0000u);
    f[6] = __uint_as_float(u.w << 16);
    f[7] = __uint_as_float(u.w & 0xffff0000u);
}

// ---------------- CSR build ----------------

__global__ __launch_bounds__(256) void k_deg(const int* edst, int* deg) {
    int e = blockIdx.x * 256 + threadIdx.x;
    if (e < N_EDGES) atomicAdd(&deg[edst[e]], 1);
}

__global__ __launch_bounds__(1024) void k_scan1(const int* deg, int* incl, int* bsum) {
    __shared__ int sd[1024];
    int b = blockIdx.x, tid = threadIdx.x;
    int gi = b * 1024 + tid;
    int v = (gi < N_NODES) ? deg[gi] : 0;
    sd[tid] = v;
    __syncthreads();
    for (int s = 1; s < 1024; s <<= 1) {
        int add = (tid >= s) ? sd[tid - s] : 0;
        __syncthreads();
        sd[tid] += add;
        __syncthreads();
    }
    if (gi < N_NODES) incl[gi] = sd[tid];
    if (tid == 1023) bsum[b] = sd[1023];
}

__global__ __launch_bounds__(1024) void k_scan3(const int* deg, const int* incl, const int* bsum,
                                                int* off, int* cursor) {
    __shared__ int bpre_s;
    int b = blockIdx.x, tid = threadIdx.x;
    if (tid == 0) {
        int acc = 0;
        for (int k = 0; k < b; k++) acc += bsum[k];
        bpre_s = acc;
    }
    __syncthreads();
    int gi = b * 1024 + tid;
    if (gi < N_NODES) {
        int e = bpre_s + incl[gi];
        off[gi + 1] = e;
        cursor[gi]  = e - deg[gi];
    }
    if (gi == 0) off[0] = 0;
}

// merged scatter + reorder: compute CSR slot, write per-edge data directly
__global__ __launch_bounds__(256) void k_scatter_reorder(const int* esrc, const int* edst,
        const float* dist, const float* swit, const float* vec, int* cursor,
        int* src_c, int* dst_c, float* dist_c, float* sc_c, float* Yf) {
    int e = blockIdx.x * 256 + threadIdx.x;
    if (e >= N_EDGES) return;
    int t_ = edst[e];
    int p = atomicAdd(&cursor[t_], 1);
    float d = dist[e];
    float inv = 1.0f / d;
    float vx = vec[(size_t)e*3 + 0] * inv;
    float vy = vec[(size_t)e*3 + 1] * inv;
    float vz = vec[(size_t)e*3 + 2] * inv;
    src_c[p]  = esrc[e];
    dst_c[p]  = t_;
    dist_c[p] = d;
    sc_c[p]   = swit[e] * 0.25f;           // switch / sqrt(ATT)
    float Y[16];
    sph16(vx, vy, vz, Y);
    #pragma unroll
    for (int m = 0; m < 16; m += 4)
        *(float4*)&Yf[(size_t)p * 16 + m] = make_float4(Y[m], Y[m+1], Y[m+2], Y[m+3]);
}

// ---------------- combined weight prep ----------------

__device__ __forceinline__ void prep_qkv_body(int bid, int tid, const float* wq,
        const float* wk, const float* wv, ushort_t* Wtq) {
    int id = bid * 256 + tid;
    if (id >= 192 * 832) return;
    int k = id / 832, n = id - (id / 832) * 832;
    float v = 0.0f;
    if (k < DIM && n < QKV_W)
        v = (n < 320) ? wq[k * 320 + n] : (n < 640) ? wk[k * 320 + (n - 320)]
                                                    : wv[k * DIM + (n - 640)];
    Wtq[(size_t)n * KQ + k] = f2bf(v);
}

__device__ __forceinline__ void prep_upd_body(int bid, int tid, const float* uw, ushort_t* Wtu) {
    int id = bid * 256 + tid;
    if (id >= 352 * 192) return;
    int k = id / 192, n = id - (id / 192) * 192;
    float v = (n < DIM) ? uw[k * DIM + n] : 0.0f;
    Wtu[(size_t)n * UI_W + k] = f2bf(v);
}

__device__ __forceinline__ void prep_mlp_body(int bid, int tid, const float* pw1,
        const float* pw2, ushort_t* w1T, ushort_t* w2T, int K1) {
    int id = bid * 256 + tid;
    if (id < 1024) {
        int n = id >> 5, k = id & 31;
        w1T[n * 32 + k] = (k < K1) ? f2bf(pw1[k * 32 + n]) : 0;
    } else if (id < 1536) {
        int id2 = id - 1024;
        int n = id2 >> 5, k = id2 & 31;
        w2T[n * 32 + k] = f2bf(pw2[k * 16 + n]);
    }
}

__global__ __launch_bounds__(256) void k_prep_all(
        const float* wq0, const float* wk0, const float* wv0, ushort_t* Wtq0,
        const float* wq1, const float* wk1, const float* wv1, ushort_t* Wtq1,
        const float* uw0, ushort_t* Wtu0, const float* uw1, ushort_t* Wtu1,
        const float* pw1_0, const float* pw2_0, ushort_t* w1T0, ushort_t* w2T0,
        const float* pw1_1, const float* pw2_1, ushort_t* w1T1, ushort_t* w2T1) {
    int bid = blockIdx.x, tid = threadIdx.x;
    if (bid < 624)        prep_qkv_body(bid,        tid, wq0, wk0, wv0, Wtq0);
    else if (bid < 1248)  prep_qkv_body(bid - 624,  tid, wq1, wk1, wv1, Wtq1);
    else if (bid < 1512)  prep_upd_body(bid - 1248, tid, uw0, Wtu0);
    else if (bid < 1776)  prep_upd_body(bid - 1512, tid, uw1, Wtu1);
    else if (bid < 1782)  prep_mlp_body(bid - 1776, tid, pw1_0, pw2_0, w1T0, w2T0, 16);
    else if (bid < 1788)  prep_mlp_body(bid - 1782, tid, pw1_1, pw2_1, w1T1, w2T1, 32);
}

// ---------------- MFMA GEMM ----------------
// OMODE: 0 = fp32 C, 1 = split bf16 qh/kh/vh

template<int KCHUNKS, int OMODE>
__global__ __launch_bounds__(256) void k_gemm(const ushort_t* __restrict__ A, int sA,
                                              const ushort_t* __restrict__ Bt, int sB,
                                              void* __restrict__ Cv, int sC, int M, int N,
                                              ushort_t* __restrict__ qh,
                                              ushort_t* __restrict__ kh,
                                              ushort_t* __restrict__ vh) {
    __shared__ ushort_t As[64 * 40];
    __shared__ ushort_t Bs[64 * 40];
    int tid  = threadIdx.x;
    int m0   = blockIdx.y * 64, n0 = blockIdx.x * 64;
    int w    = tid >> 6, lane = tid & 63, quad = lane >> 4, c16 = lane & 15;
    int arow = tid >> 2, aseg = tid & 3;
    f32x4 acc[4] = {};
    for (int kc = 0; kc < KCHUNKS; kc++) {
        int k0 = kc * 32;
        *(uint4*)&As[arow * 40 + aseg * 8] =
            *(const uint4*)&A[(size_t)(m0 + arow) * sA + k0 + aseg * 8];
        *(uint4*)&Bs[arow * 40 + aseg * 8] =
            *(const uint4*)&Bt[(size_t)(n0 + arow) * sB + k0 + aseg * 8];
        __syncthreads();
        bf16x8 a = *(const bf16x8*)&As[(w * 16 + c16) * 40 + quad * 8];
        #pragma unroll
        for (int t = 0; t < 4; t++) {
            bf16x8 b = *(const bf16x8*)&Bs[(t * 16 + c16) * 40 + quad * 8];
            acc[t] = __builtin_amdgcn_mfma_f32_16x16x32_bf16(a, b, acc[t], 0, 0, 0);
        }
        __syncthreads();
    }
    #pragma unroll
    for (int t = 0; t < 4; t++) {
        #pragma unroll
        for (int r = 0; r < 4; r++) {
            int row = m0 + w * 16 + quad * 4 + r;
            int col = n0 + t * 16 + c16;
            if (row < M && col < N) {
                if (OMODE == 1) {
                    ushort_t bv = f2bf(acc[t][r]);
                    if (col < 320)      qh[(size_t)row * QK_W + col] = bv;
                    else if (col < 640) kh[(size_t)row * QK_W + (col - 320)] = bv;
                    else                vh[(size_t)row * DIM  + (col - 640)] = bv;
                } else {
                    ((float*)Cv)[(size_t)row * sC + col] = acc[t][r];
                }
            }
        }
    }
}

// ---------------- node embedding ----------------

__global__ __launch_bounds__(256) void k_node_init(const int* species, const float* z_table,
                                                   const float* wsp, float* xi,
                                                   ushort_t* xib, ushort_t* cxm) {
    __shared__ float zs[16 * ZDIM];
    __shared__ float yt[16 * DIM];
    __shared__ float red[256];
    __shared__ float mus[16], rstds[16];
    int base = blockIdx.x * 16;
    int tid  = threadIdx.x;
    { int n = tid >> 4, kk = tid & 15;
      zs[tid] = z_table[species[base + n] * ZDIM + kk]; }
    __syncthreads();
    int c = tid;
    if (c < DIM) {
        float acc[16];
        #pragma unroll
        for (int n = 0; n < 16; n++) acc[n] = 0.0f;
        for (int kk = 0; kk < ZDIM; kk++) {
            float w = wsp[kk * DIM + c];
            #pragma unroll
            for (int n = 0; n < 16; n++) acc[n] += zs[n * ZDIM + kk] * w;
        }
        #pragma unroll
        for (int n = 0; n < 16; n++) yt[n * DIM + c] = acc[n];
    }
    __syncthreads();
    { int n2 = tid >> 4, j = tid & 15;
      float s = 0.0f;
      for (int c2 = j; c2 < DIM; c2 += 16) s += yt[n2 * DIM + c2];
      red[tid] = s; }
    __syncthreads();
    if (tid < 16) { float s = 0; for (int j = 0; j < 16; j++) s += red[tid * 16 + j]; mus[tid] = s / (float)DIM; }
    __syncthreads();
    { int n2 = tid >> 4, j = tid & 15;
      float mu = mus[n2], s = 0.0f;
      for (int c2 = j; c2 < DIM; c2 += 16) { float d = yt[n2 * DIM + c2] - mu; s += d * d; }
      red[tid] = s; }
    __syncthreads();
    if (tid < 16) { float s = 0; for (int j = 0; j < 16; j++) s += red[tid * 16 + j]; rstds[tid] = rsqrtf(s / (float)DIM + 1e-6f); }
    __syncthreads();
    if (c < DIM) {
        #pragma unroll
        for (int n = 0; n < 16; n++) {
            float val = (yt[n * DIM + c] - mus[n]) * rstds[n];
            xi[(size_t)(base + n) * DIM + c] = val;
            ushort_t bv = f2bf(val);
            xib[(size_t)(base + n) * KQ + c]   = bv;
            cxm[(size_t)(base + n) * UI_W + c] = bv;
        }
    } else if (c < KQ) {
        #pragma unroll
        for (int n = 0; n < 16; n++) xib[(size_t)(base + n) * KQ + c] = 0;
    }
}

// ---------------- fused edge kernel (R12 configuration) ----------------

template<bool L0>
__global__ __launch_bounds__(256) void k_edge(const float* dist_c, const float* sc_c,
        const int* src_c, const int* dst_c, const float* Yf, const ushort_t* Vih,
        const ushort_t* qh, const ushort_t* kh,
        const ushort_t* w1T, const float* pb1, const ushort_t* w2T, const float* pb2,
        ushort_t* aijh) {
    __shared__ ushort_t urS[64 * 40];
    __shared__ ushort_t Ht[4][16 * 40];
    __shared__ float    wdS[64 * 17];
    __shared__ ushort_t aS[NH][64];
    int tid  = threadIdx.x;
    int w    = tid >> 6, lane = tid & 63, quad = lane >> 4, c16 = lane & 15;
    int eb   = blockIdx.x * 64;

    if (!L0) {
        if (tid < 64) {
            int i = eb + tid;
            float d = dist_c[i];
            ushort_t u[32];
            #pragma unroll
            for (int r = 0; r < 16; r++) {
                float cc = 0.8f + (float)r * RSTEP;
                float uu = (d - cc) * SIGINV;
                u[r] = f2bf(__expf(-uu * uu));
            }
            float Y[16];
            #pragma unroll
            for (int m = 0; m < 16; m += 4) {
                float4 y = *(const float4*)&Yf[(size_t)i * 16 + m];
                Y[m] = y.x; Y[m+1] = y.y; Y[m+2] = y.z; Y[m+3] = y.w;
            }
            int s = src_c[i], t_ = dst_c[i];
            const uint4* vd4 = (const uint4*)(Vih + (size_t)t_ * 64);
            const uint4* vs4 = (const uint4*)(Vih + (size_t)s  * 64);
            #pragma unroll
            for (int th = 0; th < THH; th++) {
                float fd[16], fs[16];
                unpack8(vd4[2*th],   fd);     unpack8(vd4[2*th+1], fd+8);
                unpack8(vs4[2*th],   fs);     unpack8(vs4[2*th+1], fs+8);
                float us0 = (fd[0] + fs[0]) * Y[0];
                float us1 = 0.0f, us2 = 0.0f, us3 = 0.0f;
                #pragma unroll
                for (int m = 1; m < 4; m++)  us1 += (fd[m] - fs[m]) * Y[m];
                #pragma unroll
                for (int m = 4; m < 9; m++)  us2 += (fd[m] + fs[m]) * Y[m];
                #pragma unroll
                for (int m = 9; m < 16; m++) us3 += (fd[m] - fs[m]) * Y[m];
                u[16 + 0 * 4 + th] = f2bf(us0);
                u[16 + 1 * 4 + th] = f2bf(us1);
                u[16 + 2 * 4 + th] = f2bf(us2);
                u[16 + 3 * 4 + th] = f2bf(us3);
            }
            #pragma unroll
            for (int p = 0; p < 4; p++)
                *(uint4*)&urS[tid * 40 + p * 8] = *(uint4*)&u[p * 8];
        }
        __syncthreads();
    }

    {
        int e0 = eb + w * 16;
        bf16x8 a1;
        if (L0) {
            float d = dist_c[e0 + c16];
            #pragma unroll
            for (int j = 0; j < 8; j++) {
                int r = quad * 8 + j;
                float v = 0.0f;
                if (r < 16) { float cc = 0.8f + (float)r * RSTEP; float uu = (d - cc) * SIGINV; v = __expf(-uu * uu); }
                a1[j] = (short)f2bf(v);
            }
        } else {
            a1 = *(const bf16x8*)&urS[(w * 16 + c16) * 40 + quad * 8];
        }
        bf16x8 b0 = *(const bf16x8*)&w1T[c16 * 32 + quad * 8];
        bf16x8 b1 = *(const bf16x8*)&w1T[(16 + c16) * 32 + quad * 8];
        f32x4 acc0 = {}, acc1 = {};
        acc0 = __builtin_amdgcn_mfma_f32_16x16x32_bf16(a1, b0, acc0, 0, 0, 0);
        acc1 = __builtin_amdgcn_mfma_f32_16x16x32_bf16(a1, b1, acc1, 0, 0, 0);
        float bb0 = pb1[c16], bb1 = pb1[c16 + 16];
        #pragma unroll
        for (int r = 0; r < 4; r++) {
            int er = quad * 4 + r;
            float h0 = acc0[r] + bb0; h0 = h0 / (1.0f + __expf(-h0));
            float h1 = acc1[r] + bb1; h1 = h1 / (1.0f + __expf(-h1));
            Ht[w][er * 40 + c16]      = f2bf(h0);
            Ht[w][er * 40 + 16 + c16] = f2bf(h1);
        }
        __syncthreads();
        bf16x8 a2 = *(const bf16x8*)&Ht[w][c16 * 40 + quad * 8];
        bf16x8 b2 = *(const bf16x8*)&w2T[c16 * 32 + quad * 8];
        f32x4 acc2 = {};
        acc2 = __builtin_amdgcn_mfma_f32_16x16x32_bf16(a2, b2, acc2, 0, 0, 0);
        float bb2 = pb2[c16];
        #pragma unroll
        for (int r = 0; r < 4; r++) {
            int er = quad * 4 + r;
            wdS[(w * 16 + er) * 17 + c16] = (acc2[r] + bb2) * sc_c[e0 + er];
        }
    }
    __syncthreads();

    {
        int le = tid >> 2, part = tid & 3;
        int i  = eb + le;
        int s = src_c[i], t_ = dst_c[i];
        float wd[16];
        #pragma unroll
        for (int p = 0; p < 16; p++) wd[p] = wdS[le * 17 + p];
        const uint4* q4 = (const uint4*)(qh + (size_t)t_ * QK_W);
        const uint4* k4 = (const uint4*)(kh + (size_t)s  * QK_W);
        #pragma unroll
        for (int j = 0; j < 5; j++) {
            int h = part * 5 + j;
            float qa[8], qb[8], ka[8], kb[8];
            unpack8(q4[2*h],   qa); unpack8(q4[2*h+1], qb);
            unpack8(k4[2*h],   ka); unpack8(k4[2*h+1], kb);
            float acc = 0.0f;
            #pragma unroll
            for (int dd = 0; dd < 8; dd++) acc += qa[dd] * ka[dd] * wd[dd];
            #pragma unroll
            for (int dd = 0; dd < 8; dd++) acc += qb[dd] * kb[dd] * wd[8 + dd];
            aS[h][le] = f2bf(acc);
        }
    }
    __syncthreads();
    {
        const uint* aSw = (const uint*)aS;
        for (int idx = tid; idx < NH * 32; idx += 256) {
            int h = idx >> 5, w2 = idx & 31;
            *(uint*)(aijh + (size_t)h * N_EDGES + eb + w2 * 2) = aSw[h * 32 + w2];
        }
    }
}

// ---------------- aggregation: one wave per node for BOTH mi and Vi ----------

__device__ __forceinline__ void mi_step(int i, int c0, bool f1, bool f2,
        const int* src_c, const ushort_t* aA, const ushort_t* aB, const ushort_t* vh,
        float& acc0, float& acc1, float& acc2, float& acc3) {
    int s0 = src_c[i];
    uint2 v0 = *(const uint2*)(vh + (size_t)s0 * DIM + c0);
    float a00 = bf2f(aA[i]), a0B = bf2f(aB[i]);
    float g01 = f1 ? a0B : a00, g02 = f2 ? a0B : a00;
    acc0 += a00 * __uint_as_float(v0.x << 16);
    acc1 += g01 * __uint_as_float(v0.x & 0xffff0000u);
    acc2 += g02 * __uint_as_float(v0.y << 16);
    acc3 += a0B * __uint_as_float(v0.y & 0xffff0000u);
}

__device__ __forceinline__ void mi_wave(int n, int lane, const int* off, const int* src_c,
        const ushort_t* aijh, const ushort_t* vh, ushort_t* cxm) {
    if (lane >= 44) return;
    int c0 = lane * 4;
    int hA = c0 / VD;
    int hB = (c0 + 3) / VD;
    bool f1 = ((c0 + 1) / VD) != hA;
    bool f2 = ((c0 + 2) / VD) != hA;
    const ushort_t* aA = aijh + (size_t)hA * N_EDGES;
    const ushort_t* aB = aijh + (size_t)hB * N_EDGES;
    int start = off[n], end = off[n + 1];
    float acc0 = 0, acc1 = 0, acc2 = 0, acc3 = 0;
    int i = start;
    for (; i + 4 <= end; i += 4) {
        int s0 = src_c[i], s1 = src_c[i+1], s2 = src_c[i+2], s3 = src_c[i+3];
        uint2 v0 = *(const uint2*)(vh + (size_t)s0 * DIM + c0);
        uint2 v1 = *(const uint2*)(vh + (size_t)s1 * DIM + c0);
        uint2 v2 = *(const uint2*)(vh + (size_t)s2 * DIM + c0);
        uint2 v3 = *(const uint2*)(vh + (size_t)s3 * DIM + c0);
        float aA0 = bf2f(aA[i]),   aB0 = bf2f(aB[i]);
        float aA1 = bf2f(aA[i+1]), aB1 = bf2f(aB[i+1]);
        float aA2 = bf2f(aA[i+2]), aB2 = bf2f(aB[i+2]);
        float aA3 = bf2f(aA[i+3]), aB3 = bf2f(aB[i+3]);
        float g01 = f1 ? aB0 : aA0, g02 = f2 ? aB0 : aA0;
        float g11 = f1 ? aB1 : aA1, g12 = f2 ? aB1 : aA1;
        float g21 = f1 ? aB2 : aA2, g22 = f2 ? aB2 : aA2;
        float g31 = f1 ? aB3 : aA3, g32 = f2 ? aB3 : aA3;
        acc0 += aA0 * __uint_as_float(v0.x << 16);
        acc1 += g01 * __uint_as_float(v0.x & 0xffff0000u);
        acc2 += g02 * __uint_as_float(v0.y << 16);
        acc3 += aB0 * __uint_as_float(v0.y & 0xffff0000u);
        acc0 += aA1 * __uint_as_float(v1.x << 16);
        acc1 += g11 * __uint_as_float(v1.x & 0xffff0000u);
        acc2 += g12 * __uint_as_float(v1.y << 16);
        acc3 += aB1 * __uint_as_float(v1.y & 0xffff0000u);
        acc0 += aA2 * __uint_as_float(v2.x << 16);
        acc1 += g21 * __uint_as_float(v2.x & 0xffff0000u);
        acc2 += g22 * __uint_as_float(v2.y << 16);
        acc3 += aB2 * __uint_as_float(v2.y & 0xffff0000u);
        acc0 += aA3 * __uint_as_float(v3.x << 16);
        acc1 += g31 * __uint_as_float(v3.x & 0xffff0000u);
        acc2 += g32 * __uint_as_float(v3.y << 16);
        acc3 += aB3 * __uint_as_float(v3.y & 0xffff0000u);
    }
    for (; i < end; i++)
        mi_step(i, c0, f1, f2, src_c, aA, aB, vh, acc0, acc1, acc2, acc3);
    ushort_t o[4] = {f2bf(acc0), f2bf(acc1), f2bf(acc2), f2bf(acc3)};
    *(uint2*)(cxm + (size_t)n * UI_W + DIM + c0) = *(uint2*)o;
}

__device__ __forceinline__ void vi_wave(int n, int lane, const int* off,
        const float* Yf, const ushort_t* aijh, ushort_t* Vih) {
    int th = lane >> 4, sm = lane & 15;
    const ushort_t* ah = aijh + (size_t)(SH_HEADS + th) * N_EDGES;
    int start = off[n], end = off[n + 1];
    float acc = 0.0f;
    int i = start;
    for (; i + 4 <= end; i += 4) {
        float a0 = bf2f(ah[i]),   y0 = Yf[(size_t)i * 16 + sm];
        float a1 = bf2f(ah[i+1]), y1 = Yf[(size_t)(i+1) * 16 + sm];
        float a2 = bf2f(ah[i+2]), y2 = Yf[(size_t)(i+2) * 16 + sm];
        float a3 = bf2f(ah[i+3]), y3 = Yf[(size_t)(i+3) * 16 + sm];
        acc += a0 * y0 + a1 * y1 + a2 * y2 + a3 * y3;
    }
    for (; i < end; i++)
        acc += bf2f(ah[i]) * Yf[(size_t)i * 16 + sm];
    Vih[(size_t)n * 64 + lane] = f2bf(acc);
}

__global__ __launch_bounds__(256) void k_agg0(const int* off, const int* src_c,
        const float* Yf, const ushort_t* aijh, const ushort_t* vh,
        ushort_t* cxm, ushort_t* Vih) {
    int wid  = blockIdx.x * 4 + (threadIdx.x >> 6);
    int lane = threadIdx.x & 63;
    if (wid < N_NODES)
        mi_wave(wid, lane, off, src_c, aijh, vh, cxm);
    else
        vi_wave(wid - N_NODES, lane, off, Yf, aijh, Vih);
}

__global__ __launch_bounds__(256) void k_agg1(const int* off, const int* src_c,
        const ushort_t* aijh, const ushort_t* vh, ushort_t* cxm) {
    int wid  = blockIdx.x * 4 + (threadIdx.x >> 6);
    int lane = threadIdx.x & 63;
    mi_wave(wid, lane, off, src_c, aijh, vh, cxm);
}

// ---------------- LN epilogue ----------------

__global__ __launch_bounds__(256) void k_lnfinal(const float* yg, const float* xi,
        const float* ub, float* xo, ushort_t* xib, ushort_t* cxm) {
    __shared__ float yt[16 * DIM];
    __shared__ float red[256];
    __shared__ float mus[16], rstds[16];
    int base = blockIdx.x * 16;
    int tid  = threadIdx.x;
    for (int idx = tid; idx < 16 * DIM; idx += 256) {
        int n = idx / DIM, c = idx - n * DIM;
        yt[idx] = xi[(size_t)(base + n) * DIM + c]
                + yg[(size_t)(base + n) * DIM + c] + ub[c];
    }
    __syncthreads();
    { int n2 = tid >> 4, j = tid & 15;
      float s = 0.0f;
      for (int c2 = j; c2 < DIM; c2 += 16) s += yt[n2 * DIM + c2];
      red[tid] = s; }
    __syncthreads();
    if (tid < 16) { float s = 0; for (int j = 0; j < 16; j++) s += red[tid * 16 + j]; mus[tid] = s / (float)DIM; }
    __syncthreads();
    { int n2 = tid >> 4, j = tid & 15;
      float mu = mus[n2], s = 0.0f;
      for (int c2 = j; c2 < DIM; c2 += 16) { float d = yt[n2 * DIM + c2] - mu; s += d * d; }
      red[tid] = s; }
    __syncthreads();
    if (tid < 16) { float s = 0; for (int j = 0; j < 16; j++) s += red[tid * 16 + j]; rstds[tid] = rsqrtf(s / (float)DIM + 1e-6f); }
    __syncthreads();
    int c = tid;
    if (c < DIM) {
        #pragma unroll
        for (int n = 0; n < 16; n++) {
            float val = (yt[n * DIM + c] - mus[n]) * rstds[n];
            xo[(size_t)(base + n) * DIM + c] = val;
            ushort_t bv = f2bf(val);
            xib[(size_t)(base + n) * KQ + c]   = bv;
            cxm[(size_t)(base + n) * UI_W + c] = bv;
        }
    } else if (c < KQ) {
        #pragma unroll
        for (int n = 0; n < 16; n++) xib[(size_t)(base + n) * KQ + c] = 0;
    }
}

// ---------------- launch ----------------

extern "C" void kernel_launch(void* const* d_in, const int* in_sizes, int n_in,
                              void* d_out, int out_size, void* d_ws, size_t ws_size,
                              hipStream_t stream) {
    const int*   species = (const int*)  d_in[0];
    const float* dist    = (const float*)d_in[1];
    const float* swit    = (const float*)d_in[2];
    const int*   esrc    = (const int*)  d_in[3];
    const int*   edst    = (const int*)  d_in[4];
    const float* vec     = (const float*)d_in[5];
    const float* z_table = (const float*)d_in[6];
    const float* wsp     = (const float*)d_in[7];
    const float* pw1_0 = (const float*)d_in[8],  *pb1_0 = (const float*)d_in[9];
    const float* pw2_0 = (const float*)d_in[10], *pb2_0 = (const float*)d_in[11];
    const float* wq0 = (const float*)d_in[12], *wk0 = (const float*)d_in[13];
    const float* wv0 = (const float*)d_in[14], *uw0 = (const float*)d_in[15];
    const float* ub0 = (const float*)d_in[16];
    const float* pw1_1 = (const float*)d_in[17], *pb1_1 = (const float*)d_in[18];
    const float* pw2_1 = (const float*)d_in[19], *pb2_1 = (const float*)d_in[20];
    const float* wq1 = (const float*)d_in[21], *wk1 = (const float*)d_in[22];
    const float* wv1 = (const float*)d_in[23], *uw1 = (const float*)d_in[24];
    const float* ub1 = (const float*)d_in[25];
    float* out = (float*)d_out;

    char* p = (char*)d_ws;
    auto alloc = [&](size_t bytes) -> char* {
        char* r = p;
        p += (bytes + 255) & ~(size_t)255;
        return r;
    };
    int* deg    = (int*)alloc((size_t)N_NODES * 4);
    int* incl   = (int*)alloc((size_t)N_NODES * 4);
    int* bsum   = (int*)alloc(64);
    int* off    = (int*)alloc((size_t)(N_NODES + 1) * 4);
    int* cursor = (int*)alloc((size_t)N_NODES * 4);
    int*   src_c  = (int*)  alloc((size_t)N_EDGES * 4);
    int*   dst_c  = (int*)  alloc((size_t)N_EDGES * 4);
    float* dist_c = (float*)alloc((size_t)N_EDGES * 4);
    float* sc_c   = (float*)alloc((size_t)N_EDGES * 4);
    float* Yf     = (float*)alloc((size_t)N_EDGES * 16 * 4);
    float* xiA  = (float*)alloc((size_t)N_NODES * DIM * 4);
    float* xiB  = (float*)alloc((size_t)N_NODES * DIM * 4);
    ushort_t* xib  = (ushort_t*)alloc((size_t)N_PAD * KQ * 2);
    ushort_t* cxm  = (ushort_t*)alloc((size_t)N_PAD * UI_W * 2);
    ushort_t* qh   = (ushort_t*)alloc((size_t)N_NODES * QK_W * 2);
    ushort_t* kh   = (ushort_t*)alloc((size_t)N_NODES * QK_W * 2);
    ushort_t* vh   = (ushort_t*)alloc((size_t)N_NODES * DIM * 2);
    float* ybuf    = (float*)alloc((size_t)N_NODES * DIM * 4);
    ushort_t* Wtq0 = (ushort_t*)alloc((size_t)832 * KQ * 2);
    ushort_t* Wtq1 = (ushort_t*)alloc((size_t)832 * KQ * 2);
    ushort_t* Wtu0 = (ushort_t*)alloc((size_t)192 * UI_W * 2);
    ushort_t* Wtu1 = (ushort_t*)alloc((size_t)192 * UI_W * 2);
    ushort_t* w1T0 = (ushort_t*)alloc((size_t)32 * 32 * 2);
    ushort_t* w2T0 = (ushort_t*)alloc((size_t)16 * 32 * 2);
    ushort_t* w1T1 = (ushort_t*)alloc((size_t)32 * 32 * 2);
    ushort_t* w2T1 = (ushort_t*)alloc((size_t)16 * 32 * 2);
    ushort_t* Vih  = (ushort_t*)alloc((size_t)N_NODES * 64 * 2);
    ushort_t* aijh = (ushort_t*)alloc((size_t)N_EDGES * NH * 2);

    const int NB_E  = (N_EDGES + 255) / 256;   // 1250
    const int NB_F  = N_EDGES / 64;            // 5000 (fused edge kernel)
    const int NB_T  = N_NODES / 16;            // 625
    const dim3 GRID_QKV(13, 157);
    const dim3 GRID_UPD(3, 157);

    hipMemsetAsync(deg, 0, (size_t)N_NODES * 4, stream);
    k_deg<<<NB_E, 256, 0, stream>>>(edst, deg);
    k_scan1<<<10, 1024, 0, stream>>>(deg, incl, bsum);
    k_scan3<<<10, 1024, 0, stream>>>(deg, incl, bsum, off, cursor);
    k_scatter_reorder<<<NB_E, 256, 0, stream>>>(esrc, edst, dist, swit, vec, cursor,
                                                src_c, dst_c, dist_c, sc_c, Yf);

    k_prep_all<<<1788, 256, 0, stream>>>(wq0, wk0, wv0, Wtq0, wq1, wk1, wv1, Wtq1,
                                         uw0, Wtu0, uw1, Wtu1,
                                         pw1_0, pw2_0, w1T0, w2T0,
                                         pw1_1, pw2_1, w1T1, w2T1);

    k_node_init<<<NB_T, 256, 0, stream>>>(species, z_table, wsp, xiA, xib, cxm);

    // layer 0
    k_gemm<6, 1><<<GRID_QKV, 256, 0, stream>>>(xib, KQ, Wtq0, KQ, nullptr, 0,
                                               N_NODES, QKV_W, qh, kh, vh);
    k_edge<true><<<NB_F, 256, 0, stream>>>(dist_c, sc_c, src_c, dst_c, Yf, Vih,
                                           qh, kh, w1T0, pb1_0, w2T0, pb2_0, aijh);
    k_agg0<<<5000, 256, 0, stream>>>(off, src_c, Yf, aijh, vh, cxm, Vih);
    k_gemm<11, 0><<<GRID_UPD, 256, 0, stream>>>(cxm, UI_W, Wtu0, UI_W, ybuf, DIM,
                                                N_NODES, DIM, nullptr, nullptr, nullptr);
    k_lnfinal<<<NB_T, 256, 0, stream>>>(ybuf, xiA, ub0, xiB, xib, cxm);

    // layer 1
    k_gemm<6, 1><<<GRID_QKV, 256, 0, stream>>>(xib, KQ, Wtq1, KQ, nullptr, 0,
                                               N_NODES, QKV_W, qh, kh, vh);
    k_edge<false><<<NB_F, 256, 0, stream>>>(dist_c, sc_c, src_c, dst_c, Yf, Vih,
                                            qh, kh, w1T1, pb1_1, w2T1, pb2_1, aijh);
    k_agg1<<<2500, 256, 0, stream>>>(off, src_c, aijh, vh, cxm);
    k_gemm<11, 0><<<GRID_UPD, 256, 0, stream>>>(cxm, UI_W, Wtu1, UI_W, ybuf, DIM,
                                                N_NODES, DIM, nullptr, nullptr, nullptr);
    k_lnfinal<<<NB_T, 256, 0, stream>>>(ybuf, xiB, ub1, out, xib, cxm);
}